// Round 7
// baseline (857.825 us; speedup 1.0000x reference)
//
#include <hip/hip_runtime.h>
#include <math.h>

// PhaseRefinement fused kernel, v7: coarse-grained double-buffered groups.
// Lesson ladder: R2/R6 showed per-chunk sync (compute 300cyc < latency
// 900cyc) exposes a stall every 256 columns no matter how the waits are
// written; R4/R6 showed fine-grained counted-vmcnt fights the compiler's
// own conservative waits. Fix: barrier per GROUP of 4 chunks (1024 cols).
// Per-group compute (~512 FMA ~ 1100+ cyc) exceeds HBM latency, so the
// stage of group g+1 (issued before computing group g) fully lands before
// the plain __syncthreads() at group end. 6 barriers/block total.
//  - x staged once per block into LDS (kills R3/R5's 8x redundant L2 reads)
//  - W read per-wave from global (L2-resident 512KB, compiler-scheduled
//    under the FMA stream; 128-VGPR budget so loads batch)
//  - groups double-buffered: 2 x 32 KB LDS
//
// out = x + LN(c*x)*gamma + beta; LN(c*x) collapses to
//   normed = gamma*(alpha*x - alpha*mu) + beta,
//   alpha = c*rsqrt(c^2*var + 1e-5), mu/var = plain row stats of x.

constexpr int Dh     = 4096;
constexpr int Ph     = 16;
constexpr int NPL    = 32;
constexpr int CHUNK  = 256;           // 64 lanes * 4 floats
constexpr int GCHUNK = 4;             // chunks per group
constexpr int GCOLS  = CHUNK * GCHUNK;       // 1024
constexpr int NGRP   = Dh / GCOLS;    // 4
constexpr int RPB    = 8;             // rows per block
constexpr int NW     = 8;             // waves per block
constexpr int PPW    = NPL / NW;      // 4 planes per wave
constexpr int BLOCK  = 64 * NW;       // 512

__device__ __forceinline__ void stage_chunk(const float* src, float* ldsdst) {
    __builtin_amdgcn_global_load_lds(
        (const __attribute__((address_space(1))) void*)src,
        (__attribute__((address_space(3))) void*)ldsdst, 16, 0, 0);
}

__global__ __launch_bounds__(BLOCK, 2)
void phase_fused(const float* __restrict__ x,
                 const float* __restrict__ Wr,
                 const float* __restrict__ br,
                 const float* __restrict__ Wo,
                 const float* __restrict__ bo,
                 const float* __restrict__ gamma,
                 const float* __restrict__ beta,
                 float* __restrict__ out)
{
    __shared__ float x_lds[2][GCHUNK][RPB][CHUNK];   // 64 KB double buffer
    __shared__ float dots_lds[RPB][NPL];
    __shared__ float stats_lds[RPB][2];
    __shared__ float scale_lds[RPB][2];

    const int t    = threadIdx.x;
    const int wv   = t >> 6;
    const int lane = t & 63;
    const size_t rowbase = (size_t)blockIdx.x * RPB;

    // Wave wv's 4 W rows (planes wv*4..+3; 0..15 refine, 16..31 out), lane-folded.
    const float* wrow[PPW];
#pragma unroll
    for (int p = 0; p < PPW; ++p) {
        const int q = wv * PPW + p;
        wrow[p] = ((q < Ph) ? (Wr + (size_t)q * Dh) : (Wo + (size_t)(q - Ph) * Dh))
                  + lane * 4;
    }
    // Wave wv stages row wv; global src per-lane, LDS dst wave-uniform linear.
    const float* xsrc = x + (rowbase + wv) * (size_t)Dh + lane * 4;

    float acc[RPB][PPW];
#pragma unroll
    for (int r = 0; r < RPB; ++r)
#pragma unroll
        for (int p = 0; p < PPW; ++p) acc[r][p] = 0.f;
    float sx = 0.f, sxx = 0.f;

    // Prologue: stage group 0 into buf 0 (one exposed latency per block).
#pragma unroll
    for (int k = 0; k < GCHUNK; ++k)
        stage_chunk(xsrc + (size_t)k * CHUNK, &x_lds[0][k][wv][0]);
    __syncthreads();

    for (int g = 0; g < NGRP; ++g) {
        // Issue next group's stage first; it lands during this group's compute.
        if (g + 1 < NGRP) {
#pragma unroll
            for (int k = 0; k < GCHUNK; ++k)
                stage_chunk(xsrc + (size_t)((g + 1) * GCHUNK + k) * CHUNK,
                            &x_lds[(g + 1) & 1][k][wv][0]);
        }
        const float* xb = &x_lds[g & 1][0][0][0];
#pragma unroll
        for (int k = 0; k < GCHUNK; ++k) {
            const int off = (g * GCHUNK + k) * CHUNK;
            float4 w4[PPW];
#pragma unroll
            for (int p = 0; p < PPW; ++p)
                w4[p] = *(const float4*)(wrow[p] + off);
            float4 x4[RPB];
#pragma unroll
            for (int r = 0; r < RPB; ++r)
                x4[r] = *(const float4*)(xb + (k * RPB + r) * CHUNK + lane * 4);

#pragma unroll
            for (int r = 0; r < RPB; ++r) {
                if (r == wv) {   // wave-uniform; static indices
                    sx  += x4[r].x + x4[r].y + x4[r].z + x4[r].w;
                    sxx += x4[r].x*x4[r].x + x4[r].y*x4[r].y
                         + x4[r].z*x4[r].z + x4[r].w*x4[r].w;
                }
#pragma unroll
                for (int p = 0; p < PPW; ++p)
                    acc[r][p] += x4[r].x*w4[p].x + x4[r].y*w4[p].y
                               + x4[r].z*w4[p].z + x4[r].w*w4[p].w;
            }
        }
        __syncthreads();   // stage(g+1) complete (vmcnt0 drain, fully covered);
                           // buf (g+1)&1 readers done before next overwrite
    }

    // Butterfly-reduce accumulators across the 64 lanes.
#pragma unroll
    for (int r = 0; r < RPB; ++r)
#pragma unroll
        for (int p = 0; p < PPW; ++p) {
            float v = acc[r][p];
#pragma unroll
            for (int m = 1; m < 64; m <<= 1) v += __shfl_xor(v, m, 64);
            if (lane == 0) dots_lds[r][wv * PPW + p] = v;
        }
#pragma unroll
    for (int m = 1; m < 64; m <<= 1) {
        sx  += __shfl_xor(sx, m, 64);
        sxx += __shfl_xor(sxx, m, 64);
    }
    if (lane == 0) { stats_lds[wv][0] = sx; stats_lds[wv][1] = sxx; }
    __syncthreads();

    // Scalar phase, parallel over (row, plane): 128 threads, 16-lane reduce.
    if (t < RPB * Ph) {
        const int r = t >> 4, p = t & 15;
        float d1 = dots_lds[r][p]      + br[p];
        float d2 = dots_lds[r][Ph + p] + bo[p];
        float cd = cosf((tanhf(d1) - tanhf(d2)) * 3.14159265358979323846f);
#pragma unroll
        for (int m = 1; m < 16; m <<= 1) cd += __shfl_xor(cd, m, 16);
        if (p == 0) {
            float s    = cd;
            float gain = log1pf(expf(s * (1.f / Ph) + 0.5f));  // softplus
            float cm   = s * gain * (1.f / Ph);
            float mu   = stats_lds[r][0] * (1.f / Dh);
            float var  = stats_lds[r][1] * (1.f / Dh) - mu * mu;
            var = fmaxf(var, 0.f);
            float rstd  = rsqrtf(cm * cm * var + 1e-5f);
            float alpha = cm * rstd;
            scale_lds[r][0] = alpha;
            scale_lds[r][1] = alpha * mu;
        }
    }
    __syncthreads();

    // Phase B, column-sliced: wave wv owns cols [wv*512, wv*512+512);
    // gamma/beta loaded ONCE per wave, reused across all 8 rows. x re-read
    // is L2-hot (FETCH_SIZE ~= x-once at HBM every round).
    {
        const int col0 = wv * 512 + lane * 4;
        const float4 g4a = *(const float4*)(gamma + col0);
        const float4 g4b = *(const float4*)(gamma + col0 + 256);
        const float4 b4a = *(const float4*)(beta  + col0);
        const float4 b4b = *(const float4*)(beta  + col0 + 256);
#pragma unroll
        for (int r = 0; r < RPB; ++r) {
            const float alpha = scale_lds[r][0];
            const float am    = scale_lds[r][1];
            const float* xr  = x   + (rowbase + r) * (size_t)Dh;
            float*       orw = out + (rowbase + r) * (size_t)Dh;
            float4 xa = *(const float4*)(xr + col0);
            float4 xb = *(const float4*)(xr + col0 + 256);
            float4 oa, ob;
            oa.x = xa.x + g4a.x * (alpha * xa.x - am) + b4a.x;
            oa.y = xa.y + g4a.y * (alpha * xa.y - am) + b4a.y;
            oa.z = xa.z + g4a.z * (alpha * xa.z - am) + b4a.z;
            oa.w = xa.w + g4a.w * (alpha * xa.w - am) + b4a.w;
            ob.x = xb.x + g4b.x * (alpha * xb.x - am) + b4b.x;
            ob.y = xb.y + g4b.y * (alpha * xb.y - am) + b4b.y;
            ob.z = xb.z + g4b.z * (alpha * xb.z - am) + b4b.z;
            ob.w = xb.w + g4b.w * (alpha * xb.w - am) + b4b.w;
            *(float4*)(orw + col0)       = oa;
            *(float4*)(orw + col0 + 256) = ob;
        }
    }
}

extern "C" void kernel_launch(void* const* d_in, const int* in_sizes, int n_in,
                              void* d_out, int out_size, void* d_ws, size_t ws_size,
                              hipStream_t stream)
{
    const float* x     = (const float*)d_in[0];
    const float* Wr    = (const float*)d_in[1];
    const float* br    = (const float*)d_in[2];
    const float* Wo    = (const float*)d_in[3];
    const float* bo    = (const float*)d_in[4];
    const float* gamma = (const float*)d_in[5];
    const float* beta  = (const float*)d_in[6];
    float* out = (float*)d_out;

    const int B = in_sizes[0] / Dh;       // 32768
    dim3 grid(B / RPB);                   // 4096 blocks
    phase_fused<<<grid, BLOCK, 0, stream>>>(x, Wr, br, Wo, bo, gamma, beta, out);
}

// Round 8
// 474.537 us; speedup vs baseline: 1.8077x; 1.8077x over previous
//
#include <hip/hip_runtime.h>
#include <math.h>

// PhaseRefinement fused kernel, v8 = v5 (best: 415us kernel) + T19
// sched_group_barrier load-batching.
// Diagnosis ladder: v5's main loop is latency-serialized -- the compiler
// keeps only ~3-4 of the 12 independent per-chunk loads in flight (it
// minimized to 60 VGPR when ~116 was affordable), so each 256-column chunk
// pays ~3-4 sequential L2 latencies. Structural fixes (LDS rings v6, coarse
// groups v7) fought compiler waits or spilled (v7 WRITE=1.75GB). v8 keeps
// v5's proven barrier-free structure and adds per-chunk
// sched_group_barrier(VMEM_READ x13, VALU x150): all loads issue
// back-to-back, one batched latency per chunk instead of 3-4.
// Stats branch removed from the body (single scheduling region): row-wv
// stats come from a dedicated 13th load via a precomputed pointer (L1-hot).
//
// out = x + LN(c*x)*gamma + beta; LN(c*x) collapses to
//   normed = gamma*(alpha*x - alpha*mu) + beta,
//   alpha = c*rsqrt(c^2*var + 1e-5), mu/var = plain row stats of x.

constexpr int Dh     = 4096;
constexpr int Ph     = 16;
constexpr int NPL    = 32;          // 2*P dots per row
constexpr int CHUNK  = 256;         // 64 lanes * 4 floats
constexpr int NCHUNK = Dh / CHUNK;  // 16
constexpr int RPB    = 8;           // rows per block
constexpr int NW     = 8;           // waves per block
constexpr int PPW    = NPL / NW;    // 4 planes per wave
constexpr int BLOCK  = 64 * NW;     // 512

__global__ __launch_bounds__(BLOCK, 2)
void phase_fused(const float* __restrict__ x,
                 const float* __restrict__ Wr,
                 const float* __restrict__ br,
                 const float* __restrict__ Wo,
                 const float* __restrict__ bo,
                 const float* __restrict__ gamma,
                 const float* __restrict__ beta,
                 float* __restrict__ out)
{
    __shared__ float dots_lds[RPB][NPL];
    __shared__ float stats_lds[RPB][2];
    __shared__ float scale_lds[RPB][2];

    const int t    = threadIdx.x;
    const int wv   = t >> 6;
    const int lane = t & 63;
    const size_t rowbase = (size_t)blockIdx.x * RPB;

    // Per-lane base pointers (lane offset folded in).
    const float* xrow[RPB];
#pragma unroll
    for (int r = 0; r < RPB; ++r)
        xrow[r] = x + (rowbase + r) * (size_t)Dh + lane * 4;

    const float* wrow[PPW];
#pragma unroll
    for (int p = 0; p < PPW; ++p) {
        const int q = wv * PPW + p;
        wrow[p] = ((q < Ph) ? (Wr + (size_t)q * Dh) : (Wo + (size_t)(q - Ph) * Dh))
                  + lane * 4;
    }
    // Dedicated stats pointer for row wv (runtime wv resolved ONCE, here).
    const float* xstat = x + (rowbase + wv) * (size_t)Dh + lane * 4;

    float acc[RPB][PPW];
#pragma unroll
    for (int r = 0; r < RPB; ++r)
#pragma unroll
        for (int p = 0; p < PPW; ++p) acc[r][p] = 0.f;
    float sx = 0.f, sxx = 0.f;

    for (int c = 0; c < NCHUNK; ++c) {
        const int off = c * CHUNK;
        // 13 independent loads (8 x rows + 4 W planes + 1 stats re-read).
        float4 x4[RPB];
#pragma unroll
        for (int r = 0; r < RPB; ++r)
            x4[r] = *(const float4*)(xrow[r] + off);
        float4 w4[PPW];
#pragma unroll
        for (int p = 0; p < PPW; ++p)
            w4[p] = *(const float4*)(wrow[p] + off);
        float4 xs = *(const float4*)(xstat + off);

        sx  += xs.x + xs.y + xs.z + xs.w;
        sxx += xs.x*xs.x + xs.y*xs.y + xs.z*xs.z + xs.w*xs.w;

#pragma unroll
        for (int r = 0; r < RPB; ++r)
#pragma unroll
            for (int p = 0; p < PPW; ++p)
                acc[r][p] += x4[r].x*w4[p].x + x4[r].y*w4[p].y
                           + x4[r].z*w4[p].z + x4[r].w*w4[p].w;

        // T19: force the schedule [13 VMEM_READ back-to-back][VALU block]
        // per chunk. One batched memory latency per chunk instead of the
        // compiler's serialized 3-4 (it refuses to batch on its own: v5
        // compiled to 60 VGPR with ~3 loads in flight).
        __builtin_amdgcn_sched_group_barrier(0x0020, 13, 0);  // VMEM_READ
        __builtin_amdgcn_sched_group_barrier(0x0002, 160, 0); // VALU (FMAs+stats)
    }

    // Butterfly-reduce accumulators across the 64 lanes.
#pragma unroll
    for (int r = 0; r < RPB; ++r)
#pragma unroll
        for (int p = 0; p < PPW; ++p) {
            float v = acc[r][p];
#pragma unroll
            for (int m = 1; m < 64; m <<= 1) v += __shfl_xor(v, m, 64);
            if (lane == 0) dots_lds[r][wv * PPW + p] = v;
        }
#pragma unroll
    for (int m = 1; m < 64; m <<= 1) {
        sx  += __shfl_xor(sx, m, 64);
        sxx += __shfl_xor(sxx, m, 64);
    }
    if (lane == 0) { stats_lds[wv][0] = sx; stats_lds[wv][1] = sxx; }
    __syncthreads();

    // Scalar phase, parallel over (row, plane): 128 threads, 16-lane reduce.
    if (t < RPB * Ph) {
        const int r = t >> 4, p = t & 15;
        float d1 = dots_lds[r][p]      + br[p];
        float d2 = dots_lds[r][Ph + p] + bo[p];
        float cd = cosf((tanhf(d1) - tanhf(d2)) * 3.14159265358979323846f);
#pragma unroll
        for (int m = 1; m < 16; m <<= 1) cd += __shfl_xor(cd, m, 16);
        if (p == 0) {
            float s    = cd;
            float gain = log1pf(expf(s * (1.f / Ph) + 0.5f));  // softplus
            float cm   = s * gain * (1.f / Ph);
            float mu   = stats_lds[r][0] * (1.f / Dh);
            float var  = stats_lds[r][1] * (1.f / Dh) - mu * mu;
            var = fmaxf(var, 0.f);
            float rstd  = rsqrtf(cm * cm * var + 1e-5f);
            float alpha = cm * rstd;
            scale_lds[r][0] = alpha;
            scale_lds[r][1] = alpha * mu;
        }
    }
    __syncthreads();

    // Phase B, column-sliced: wave wv owns cols [wv*512, wv*512+512);
    // gamma/beta loaded ONCE per wave, reused across all 8 rows. x re-read
    // is L2-hot (FETCH_SIZE ~= x-once at HBM every round).
    {
        const int col0 = wv * 512 + lane * 4;
        const float4 g4a = *(const float4*)(gamma + col0);
        const float4 g4b = *(const float4*)(gamma + col0 + 256);
        const float4 b4a = *(const float4*)(beta  + col0);
        const float4 b4b = *(const float4*)(beta  + col0 + 256);
#pragma unroll
        for (int r = 0; r < RPB; ++r) {
            const float alpha = scale_lds[r][0];
            const float am    = scale_lds[r][1];
            const float* xr  = x   + (rowbase + r) * (size_t)Dh;
            float*       orw = out + (rowbase + r) * (size_t)Dh;
            float4 xa = *(const float4*)(xr + col0);
            float4 xb = *(const float4*)(xr + col0 + 256);
            float4 oa, ob;
            oa.x = xa.x + g4a.x * (alpha * xa.x - am) + b4a.x;
            oa.y = xa.y + g4a.y * (alpha * xa.y - am) + b4a.y;
            oa.z = xa.z + g4a.z * (alpha * xa.z - am) + b4a.z;
            oa.w = xa.w + g4a.w * (alpha * xa.w - am) + b4a.w;
            ob.x = xb.x + g4b.x * (alpha * xb.x - am) + b4b.x;
            ob.y = xb.y + g4b.y * (alpha * xb.y - am) + b4b.y;
            ob.z = xb.z + g4b.z * (alpha * xb.z - am) + b4b.z;
            ob.w = xb.w + g4b.w * (alpha * xb.w - am) + b4b.w;
            *(float4*)(orw + col0)       = oa;
            *(float4*)(orw + col0 + 256) = ob;
        }
    }
}

extern "C" void kernel_launch(void* const* d_in, const int* in_sizes, int n_in,
                              void* d_out, int out_size, void* d_ws, size_t ws_size,
                              hipStream_t stream)
{
    const float* x     = (const float*)d_in[0];
    const float* Wr    = (const float*)d_in[1];
    const float* br    = (const float*)d_in[2];
    const float* Wo    = (const float*)d_in[3];
    const float* bo    = (const float*)d_in[4];
    const float* gamma = (const float*)d_in[5];
    const float* beta  = (const float*)d_in[6];
    float* out = (float*)d_out;

    const int B = in_sizes[0] / Dh;       // 32768
    dim3 grid(B / RPB);                   // 4096 blocks
    phase_fused<<<grid, BLOCK, 0, stream>>>(x, Wr, br, Wo, bo, gamma, beta, out);
}